// Round 8
// baseline (632.937 us; speedup 1.0000x reference)
//
#include <hip/hip_runtime.h>

#define T_STEPS 1024
#define BATCH   1024
#define NS      64
#define CPB     16                      // chains per block (MFMA N dim)
#define NBLK    (BATCH / CPB)           // 64 blocks
#define TS      ((size_t)BATCH * NS)    // floats per timestep plane

typedef __attribute__((ext_vector_type(8))) __bf16 bf16x8;
typedef __attribute__((ext_vector_type(4))) float  f32x4;

// ds_swizzle BitMode xor-16 within each 32-lane group
#define SWZ_XOR16 0x401F
__device__ __forceinline__ float swz16f(float x) {
    return __uint_as_float((unsigned)__builtin_amdgcn_ds_swizzle(
        (int)__float_as_uint(x), SWZ_XOR16));
}

// raw barrier WITHOUT the __syncthreads() vmcnt(0) drain (which would flush
// the producer's in-flight prefetch loads every group). "memory" clobber
// pins all memory ops (LDS + global issue order) to their side of it.
#define BARRIER() asm volatile("s_barrier" ::: "memory")
#define LGKM0()   asm volatile("s_waitcnt lgkmcnt(0)" ::: "memory")

// v12: producer/consumer wave split. v11 post-mortem: step time 637 cyc with
// only ~140 cyc of accounted issue; v10's exact-2x-for-2-streams result says
// the wave is stalled on something that scales with work — the em load
// latency (ring depth 4 self-balances at latency/4) and the 16 quarter-rate
// v_exp per step, BOTH of which are input preprocessing, not recurrence.
// So: wave 1 (producer) streams em, exps it, writes a 4-deep LDS group-ring
// (identity lane map: producer lane l writes exactly what consumer lane l
// needs -> conflict-free b128 on both sides). Wave 0 (consumer) runs v11's
// register-closed MFMA recurrence (phi-compensated A-gather, same-lane D->B
// repack, renorm-every-4, capture at t==Lc-1 — all index-identical) with
// exp(em) served from LDS. Producer runs 2 groups ahead in regs (rawE/rawO,
// static ring via two-group unroll) + 2 groups of LDS lag ~= 1700 cyc of
// memory-latency budget. One raw s_barrier per 4-step half; producer drains
// lgkmcnt before each barrier; buffers written 2 barriers before first read.
__global__ __launch_bounds__(128)
void crf_fwd_v12(const float* __restrict__ em,     // [T, B, S]
                 const int*   __restrict__ seqlen, // [B]
                 const float* __restrict__ start,  // [S]
                 const float* __restrict__ stop,   // [S]
                 const float* __restrict__ trans,  // [S, S]
                 float*       __restrict__ out) {  // [B]
    __shared__ f32x4 exb[4][4][4][64];   // [buf][step j][mt][lane] = 64 KB

    const int tid = threadIdx.x;
    const int wv  = tid >> 6;            // 0 = consumer, 1 = producer
    const int l   = tid & 63;
    const int c   = l & 15;
    const int g   = l >> 4;
    const int b0  = blockIdx.x * CPB;
    const int Lc  = seqlen[b0 + c];

    // block-wide max chain length (both waves compute identically -> same
    // trip count -> same barrier count)
    int tmax = Lc;
#pragma unroll
    for (int o = 1; o < 16; o <<= 1) {
        int t_ = __shfl_xor(tmax, o, 64);
        tmax = tmax > t_ ? tmax : t_;
    }
    const int NGRP = (tmax + 2) >> 2;    // groups of 4 steps covering 1..tmax-1

    const float* emB = em + (size_t)(b0 + c) * NS + 4 * g;

    // ---- consumer state (live only on wv==0 path) ----
    bf16x8 ae[4][2];
    float  es[4][4];
    float  u[4][4];
    f32x4  acc[4];
    bf16x8 bfA, bfB;
    float  mloc = 0.f, cacc = 0.f, inv = 1.f;
    // ---- producer state ----
    f32x4 rawE[4][4], rawO[4][4];        // [step j][mt], 2-group reg ring

#define CAPT(T_)                                                              \
    do {                                                                      \
        float dv_ = 0.f;                                                      \
        _Pragma("unroll") for (int m_ = 0; m_ < 4; ++m_)                      \
            _Pragma("unroll") for (int i_ = 0; i_ < 4; ++i_)                  \
                dv_ = fmaf(u[m_][i_], es[m_][i_], dv_);                       \
        dv_ += swz16f(dv_);                                                   \
        dv_ += __shfl_xor(dv_, 32, 64);                                       \
        if ((T_) == Lc - 1 && g == 0) out[b0 + c] = __logf(dv_) + cacc;       \
    } while (0)

    // same-lane D->B repack: bfA = u[0..1], bfB = u[2..3] (bf16)
#define PACKB()                                                               \
    do {                                                                      \
        bf16x8 xa_, xb_;                                                      \
        xa_[0] = (__bf16)u[0][0]; xa_[1] = (__bf16)u[0][1];                   \
        xa_[2] = (__bf16)u[0][2]; xa_[3] = (__bf16)u[0][3];                   \
        xa_[4] = (__bf16)u[1][0]; xa_[5] = (__bf16)u[1][1];                   \
        xa_[6] = (__bf16)u[1][2]; xa_[7] = (__bf16)u[1][3];                   \
        xb_[0] = (__bf16)u[2][0]; xb_[1] = (__bf16)u[2][1];                   \
        xb_[2] = (__bf16)u[2][2]; xb_[3] = (__bf16)u[2][3];                   \
        xb_[4] = (__bf16)u[3][0]; xb_[5] = (__bf16)u[3][1];                   \
        xb_[6] = (__bf16)u[3][2]; xb_[7] = (__bf16)u[3][3];                   \
        bfA = xa_; bfB = xb_;                                                 \
    } while (0)

    // one consumer step: t = 4*G_+1+J_ ; ex comes from LDS buffer G_&3
#define CSTEP(G_, J_, RN_, LAST_)                                             \
    do {                                                                      \
        const int t_ = 4 * (G_) + 1 + (J_);                                   \
        f32x4 exq[4];                                                         \
        _Pragma("unroll") for (int m_ = 0; m_ < 4; ++m_)                      \
            exq[m_] = exb[(G_) & 3][J_][m_][l];                               \
        f32x4 zz_ = {0.f, 0.f, 0.f, 0.f};                                     \
        _Pragma("unroll") for (int m_ = 0; m_ < 4; ++m_)                      \
            acc[m_] = __builtin_amdgcn_mfma_f32_16x16x32_bf16(                \
                ae[m_][0], bfA, zz_, 0, 0, 0);                                \
        _Pragma("unroll") for (int m_ = 0; m_ < 4; ++m_)                      \
            acc[m_] = __builtin_amdgcn_mfma_f32_16x16x32_bf16(                \
                ae[m_][1], bfB, acc[m_], 0, 0, 0);                            \
        if (RN_) {                                                            \
            float v1_ = fmaxf(mloc, swz16f(mloc));                            \
            float mm_ = fmaxf(v1_, __shfl_xor(v1_, 32, 64));                  \
            mm_ = fmaxf(mm_, 1e-30f);                                         \
            inv = __builtin_amdgcn_rcpf(mm_);                                 \
            cacc += __logf(mm_);                                              \
        }                                                                     \
        _Pragma("unroll") for (int m_ = 0; m_ < 4; ++m_)                      \
            _Pragma("unroll") for (int i_ = 0; i_ < 4; ++i_) {                \
                float exv_ = exq[m_][i_];                                     \
                if (RN_) exv_ *= inv;                                         \
                u[m_][i_] = acc[m_][i_] * exv_;                               \
            }                                                                 \
        if (__any(t_ == Lc - 1)) CAPT(t_);                                    \
        if (LAST_) {                                                          \
            mloc = u[0][0];                                                   \
            _Pragma("unroll") for (int m_ = 0; m_ < 4; ++m_)                  \
                _Pragma("unroll") for (int i_ = 0; i_ < 4; ++i_)              \
                    mloc = fmaxf(mloc, u[m_][i_]);                            \
        }                                                                     \
        PACKB();                                                              \
    } while (0)

#define CGRP(G_)                                                              \
    do {                                                                      \
        CSTEP(G_, 0, 1, 0);                                                   \
        CSTEP(G_, 1, 0, 0);                                                   \
        CSTEP(G_, 2, 0, 0);                                                   \
        CSTEP(G_, 3, 0, 1);                                                   \
    } while (0)

    // producer half: exp+write buffer for group W_ from RAW_, then reload
    // RAW_ with group L_ (consumed one big-iter = 2 barriers+ later)
#define PHALF(W_, RAW_, L_)                                                   \
    do {                                                                      \
        const int bw_ = (W_) & 3;                                             \
        _Pragma("unroll") for (int j_ = 0; j_ < 4; ++j_)                      \
            _Pragma("unroll") for (int m_ = 0; m_ < 4; ++m_) {                \
                f32x4 r_ = RAW_[j_][m_], x_;                                  \
                x_[0] = __expf(r_[0]); x_[1] = __expf(r_[1]);                 \
                x_[2] = __expf(r_[2]); x_[3] = __expf(r_[3]);                 \
                exb[bw_][j_][m_][l] = x_;                                     \
            }                                                                 \
        _Pragma("unroll") for (int j_ = 0; j_ < 4; ++j_) {                    \
            int tl_ = 4 * (L_) + 1 + j_;                                      \
            if (tl_ > T_STEPS - 1) tl_ = T_STEPS - 1;                         \
            _Pragma("unroll") for (int m_ = 0; m_ < 4; ++m_)                  \
                RAW_[j_][m_] =                                                \
                    *(const f32x4*)(emB + (size_t)tl_ * TS + 16 * m_);        \
        }                                                                     \
    } while (0)

    if (wv == 0) {
        // ---- consumer prologue: E fragments (phi-compensated), es, t=0 ----
#pragma unroll
        for (int mt = 0; mt < 4; ++mt)
#pragma unroll
            for (int ks = 0; ks < 2; ++ks) {
                const float* rp =
                    trans + (size_t)(16 * mt + c) * NS + 32 * ks + 4 * g;
                f32x4 t0 = *(const f32x4*)rp;
                f32x4 t1 = *(const f32x4*)(rp + 16);
                bf16x8 a;
                a[0] = (__bf16)__expf(t0[0]); a[1] = (__bf16)__expf(t0[1]);
                a[2] = (__bf16)__expf(t0[2]); a[3] = (__bf16)__expf(t0[3]);
                a[4] = (__bf16)__expf(t1[0]); a[5] = (__bf16)__expf(t1[1]);
                a[6] = (__bf16)__expf(t1[2]); a[7] = (__bf16)__expf(t1[3]);
                ae[mt][ks] = a;
            }
#pragma unroll
        for (int mt = 0; mt < 4; ++mt) {
            f32x4 sv = *(const f32x4*)(stop + 16 * mt + 4 * g);
#pragma unroll
            for (int i = 0; i < 4; ++i) es[mt][i] = __expf(sv[i]);
        }
#pragma unroll
        for (int mt = 0; mt < 4; ++mt) {
            f32x4 e0 = *(const f32x4*)(emB + 16 * mt);   // t = 0
            f32x4 sv = *(const f32x4*)(start + 16 * mt + 4 * g);
#pragma unroll
            for (int i = 0; i < 4; ++i)
                u[mt][i] = __expf(sv[i] + e0[i]);
        }
        cacc = 0.f; inv = 1.f; (void)inv;
        if (__any(0 == Lc - 1)) CAPT(0);
        mloc = u[0][0];
#pragma unroll
        for (int mt = 0; mt < 4; ++mt)
#pragma unroll
            for (int i = 0; i < 4; ++i) mloc = fmaxf(mloc, u[mt][i]);
        PACKB();
    } else {
        // ---- producer prologue: groups 0,1 -> LDS; groups 2,3 -> reg ring --
#pragma unroll
        for (int W = 0; W < 2; ++W) {
            f32x4 tmp[4][4];
#pragma unroll
            for (int j = 0; j < 4; ++j) {
                int t = 4 * W + 1 + j;
                if (t > T_STEPS - 1) t = T_STEPS - 1;
#pragma unroll
                for (int mt = 0; mt < 4; ++mt)
                    tmp[j][mt] = *(const f32x4*)(emB + (size_t)t * TS + 16 * mt);
            }
#pragma unroll
            for (int j = 0; j < 4; ++j)
#pragma unroll
                for (int mt = 0; mt < 4; ++mt) {
                    f32x4 r = tmp[j][mt], x;
                    x[0] = __expf(r[0]); x[1] = __expf(r[1]);
                    x[2] = __expf(r[2]); x[3] = __expf(r[3]);
                    exb[W][j][mt][l] = x;
                }
        }
#pragma unroll
        for (int j = 0; j < 4; ++j) {
            int t2 = 4 * 2 + 1 + j; if (t2 > T_STEPS - 1) t2 = T_STEPS - 1;
            int t3 = 4 * 3 + 1 + j; if (t3 > T_STEPS - 1) t3 = T_STEPS - 1;
#pragma unroll
            for (int mt = 0; mt < 4; ++mt) {
                rawE[j][mt] = *(const f32x4*)(emB + (size_t)t2 * TS + 16 * mt);
                rawO[j][mt] = *(const f32x4*)(emB + (size_t)t3 * TS + 16 * mt);
            }
        }
        LGKM0();    // ds_writes of groups 0,1 committed before first barrier
    }

    // ---- main loop: two groups per iteration (static reg-ring parity) ----
    for (int G = 0; G < NGRP; G += 2) {
        BARRIER();
        if (wv == 0) {
            CGRP(G);
        } else {
            PHALF(G + 2, rawE, G + 4);
            LGKM0();
        }
        BARRIER();
        if (wv == 0) {
            CGRP(G + 1);            // may be inert past NGRP — harmless
        } else {
            PHALF(G + 3, rawO, G + 5);
            LGKM0();
        }
    }
}

extern "C" void kernel_launch(void* const* d_in, const int* in_sizes, int n_in,
                              void* d_out, int out_size, void* d_ws, size_t ws_size,
                              hipStream_t stream) {
    const float* em     = (const float*)d_in[0]; // [T, B, S]
    const int*   seqlen = (const int*)  d_in[1]; // [B]
    const float* start  = (const float*)d_in[2]; // [S]
    const float* stop   = (const float*)d_in[3]; // [S]
    const float* trans  = (const float*)d_in[4]; // [S, S]
    float*       out    = (float*)d_out;         // [B]

    crf_fwd_v12<<<NBLK, 128, 0, stream>>>(em, seqlen, start, stop, trans, out);
}